// Round 1
// baseline (1296.363 us; speedup 1.0000x reference)
//
#include <hip/hip_runtime.h>
#include <math.h>

#define BTOT 262144
#define FDIM 256
#define KK 20
#define HH 64
#define MM 32

#define IMP_OFF  (BTOT * KK)            // 5242880
#define CWM_OFF  (IMP_OFF + KK)         // 5242900
#define ACT_OFF  (CWM_OFF + KK)         // 5242920
#define PAIR_OFF (ACT_OFF + 1)          // 5242921

__device__ __forceinline__ bool better(float v2, int p2, float v1, int p1) {
  return (v2 > v1) || (v2 == v1 && p2 < p1);
}

// ---------------- Top-K stage 1: per-row top-20 ----------------
// grid = 256 blocks (one per row i), 256 threads (one per col j)
__global__ void topk_stage1(const float* __restrict__ w,
                            float* __restrict__ cand_v, int* __restrict__ cand_p) {
  const int i = blockIdx.x;
  const int j = threadIdx.x;
  const int lane = j & 63, wid = j >> 6;
  __shared__ float sv[256];
  __shared__ float rv[4];
  __shared__ int rp[4];

  sv[j] = (j > i) ? w[i * 256 + j] : -1e30f;
  __syncthreads();

  for (int r = 0; r < 20; ++r) {
    float v = sv[j];
    int p = i * 256 + j;
    #pragma unroll
    for (int off = 32; off; off >>= 1) {
      float v2 = __shfl_down(v, off);
      int p2 = __shfl_down(p, off);
      if (better(v2, p2, v, p)) { v = v2; p = p2; }
    }
    if (lane == 0) { rv[wid] = v; rp[wid] = p; }
    __syncthreads();
    if (j == 0) {
      #pragma unroll
      for (int t = 1; t < 4; ++t)
        if (better(rv[t], rp[t], v, p)) { v = rv[t]; p = rp[t]; }
      cand_v[i * 20 + r] = v;
      cand_p[i * 20 + r] = p;
      sv[p & 255] = -2e30f;   // invalidate chosen entry
    }
    __syncthreads();
  }
}

// ---------------- Top-K stage 2: merge 256*20 candidates ----------------
#define NC 5120
__global__ void topk_stage2(const float* __restrict__ cand_v, const int* __restrict__ cand_p,
                            int* __restrict__ pij, float* __restrict__ out) {
  const int tid = threadIdx.x;
  const int lane = tid & 63, wid = tid >> 6;
  __shared__ float sv[NC];
  __shared__ int sp[NC];
  __shared__ float rv[4];
  __shared__ int rp[4], rq[4];
  __shared__ float selv[20];
  __shared__ int selp[20];

  for (int t = tid; t < NC; t += 256) { sv[t] = cand_v[t]; sp[t] = cand_p[t]; }
  __syncthreads();

  for (int r = 0; r < 20; ++r) {
    float v = -4e30f;
    int p = 0x7fffffff, q = 0;
    for (int t = tid; t < NC; t += 256) {
      float vv = sv[t];
      int pp = sp[t];
      if (better(vv, pp, v, p)) { v = vv; p = pp; q = t; }
    }
    #pragma unroll
    for (int off = 32; off; off >>= 1) {
      float v2 = __shfl_down(v, off);
      int p2 = __shfl_down(p, off);
      int q2 = __shfl_down(q, off);
      if (better(v2, p2, v, p)) { v = v2; p = p2; q = q2; }
    }
    if (lane == 0) { rv[wid] = v; rp[wid] = p; rq[wid] = q; }
    __syncthreads();
    if (tid == 0) {
      #pragma unroll
      for (int t = 1; t < 4; ++t)
        if (better(rv[t], rp[t], v, p)) { v = rv[t]; p = rp[t]; q = rq[t]; }
      selv[r] = v;
      selp[r] = p;
      sv[q] = -3e30f;
    }
    __syncthreads();
  }

  if (tid == 0) {
    int active = 0;
    for (int r = 0; r < 20; ++r) {
      int p = selp[r];
      int i = p >> 8, j = p & 255;
      float s = 1.0f / (1.0f + expf(-selv[r]));
      out[IMP_OFF + r] = s;
      out[PAIR_OFF + 2 * r] = (float)i;
      out[PAIR_OFF + 2 * r + 1] = (float)j;
      if (s > 0.1f) active++;
      pij[r] = i;
      pij[20 + r] = j;
    }
    out[ACT_OFF] = (float)active;
  }
}

// ---------------- Main: per-sample ctx MLP + 20 pair MLPs ----------------
__global__ __launch_bounds__(256, 2) void id_main(
    const float* __restrict__ x,
    const float* __restrict__ Wc1, const float* __restrict__ bc1,
    const float* __restrict__ Wc2, const float* __restrict__ bc2,
    const float* __restrict__ W1, const float* __restrict__ b1,
    const float* __restrict__ W2, const float* __restrict__ b2,
    const float* __restrict__ W3, const float* __restrict__ b3,
    const int* __restrict__ pij,
    float* __restrict__ ctx_sums,
    float* __restrict__ out) {
  __shared__ float csum[KK];
  if (threadIdx.x < KK) csum[threadIdx.x] = 0.0f;
  __syncthreads();

  const int b = blockIdx.x * 256 + threadIdx.x;
  const float* __restrict__ xr = x + (size_t)b * FDIM;

  // ---- ctx hidden layer: h = x @ Wc1 + bc1
  float h[HH];
  #pragma unroll
  for (int j = 0; j < HH; ++j) h[j] = bc1[j];
  #pragma unroll 1
  for (int f = 0; f < FDIM; f += 4) {
    const float4 xv = *(const float4*)(xr + f);
    const float* __restrict__ w0 = Wc1 + (size_t)f * HH;
    #pragma unroll
    for (int j = 0; j < HH; ++j) {
      float acc = h[j];
      acc = fmaf(xv.x, w0[j], acc);
      acc = fmaf(xv.y, w0[HH + j], acc);
      acc = fmaf(xv.z, w0[2 * HH + j], acc);
      acc = fmaf(xv.w, w0[3 * HH + j], acc);
      h[j] = acc;
    }
  }

  // ---- ctx output layer: ctx = sigmoid(relu(h) @ Wc2 + bc2)
  float ctx[KK];
  #pragma unroll
  for (int k = 0; k < KK; ++k) ctx[k] = bc2[k];
  #pragma unroll 2
  for (int j = 0; j < HH; ++j) {
    const float hj = fmaxf(h[j], 0.0f);
    const float* __restrict__ wr = Wc2 + j * KK;
    #pragma unroll
    for (int k = 0; k < KK; ++k) ctx[k] = fmaf(hj, wr[k], ctx[k]);
  }
  #pragma unroll
  for (int k = 0; k < KK; ++k) ctx[k] = 1.0f / (1.0f + expf(-ctx[k]));

  // ---- 20 pair-MLPs, software-pipelined pair gather
  float pa = xr[pij[0]];
  float pb = xr[pij[KK]];
  #pragma unroll 1
  for (int k = 0; k < KK; ++k) {
    float pan = 0.0f, pbn = 0.0f;
    if (k + 1 < KK) { pan = xr[pij[k + 1]]; pbn = xr[pij[KK + k + 1]]; }

    const float* __restrict__ w1a = W1 + (size_t)k * 2 * HH;
    const float* __restrict__ w1b = w1a + HH;
    const float* __restrict__ b1k = b1 + (size_t)k * HH;
    float h1[HH];
    #pragma unroll
    for (int j = 0; j < HH; ++j)
      h1[j] = fmaxf(fmaf(pa, w1a[j], fmaf(pb, w1b[j], b1k[j])), 0.0f);

    float h2[MM];
    const float* __restrict__ b2k = b2 + (size_t)k * MM;
    #pragma unroll
    for (int m = 0; m < MM; ++m) h2[m] = b2k[m];
    const float* __restrict__ w2k = W2 + (size_t)k * HH * MM;
    #pragma unroll 2
    for (int j = 0; j < HH; ++j) {
      const float hj = h1[j];
      const float* __restrict__ wr = w2k + j * MM;
      #pragma unroll
      for (int m = 0; m < MM; ++m) h2[m] = fmaf(hj, wr[m], h2[m]);
    }

    const float* __restrict__ w3k = W3 + (size_t)k * MM;
    float o = b3[k];
    #pragma unroll
    for (int m = 0; m < MM; ++m) o = fmaf(fmaxf(h2[m], 0.0f), w3k[m], o);

    out[(size_t)b * KK + k] = o * ctx[k];
    pa = pan;
    pb = pbn;
  }

  // ---- ctx mean accumulation: wave shuffle -> LDS -> global atomic
  const int lane = threadIdx.x & 63;
  #pragma unroll 1
  for (int k = 0; k < KK; ++k) {
    float v = ctx[k];
    #pragma unroll
    for (int off = 32; off; off >>= 1) v += __shfl_down(v, off);
    if (lane == 0) atomicAdd(&csum[k], v);
  }
  __syncthreads();
  if (threadIdx.x < KK) atomicAdd(&ctx_sums[threadIdx.x], csum[threadIdx.x]);
}

__global__ void id_finalize(const float* __restrict__ ctx_sums, float* __restrict__ out) {
  const int k = threadIdx.x;
  if (k < KK) out[CWM_OFF + k] = ctx_sums[k] * (1.0f / (float)BTOT);
}

extern "C" void kernel_launch(void* const* d_in, const int* in_sizes, int n_in,
                              void* d_out, int out_size, void* d_ws, size_t ws_size,
                              hipStream_t stream) {
  const float* x   = (const float*)d_in[0];
  const float* iw  = (const float*)d_in[1];
  const float* Wc1 = (const float*)d_in[2];
  const float* bc1 = (const float*)d_in[3];
  const float* Wc2 = (const float*)d_in[4];
  const float* bc2 = (const float*)d_in[5];
  const float* W1  = (const float*)d_in[6];
  const float* b1  = (const float*)d_in[7];
  const float* W2  = (const float*)d_in[8];
  const float* b2  = (const float*)d_in[9];
  const float* W3  = (const float*)d_in[10];
  const float* b3  = (const float*)d_in[11];
  float* out = (float*)d_out;

  float* wsf    = (float*)d_ws;
  float* cand_v = wsf;                  // 5120 floats
  int*   cand_p = (int*)(wsf + 5120);   // 5120 ints
  int*   pij    = (int*)(wsf + 10240);  // 40 ints
  float* csums  = wsf + 10280;          // 20 floats

  hipMemsetAsync(csums, 0, KK * sizeof(float), stream);
  topk_stage1<<<256, 256, 0, stream>>>(iw, cand_v, cand_p);
  topk_stage2<<<1, 256, 0, stream>>>(cand_v, cand_p, pij, out);
  id_main<<<BTOT / 256, 256, 0, stream>>>(x, Wc1, bc1, Wc2, bc2, W1, b1, W2, b2, W3, b3,
                                          pij, csums, out);
  id_finalize<<<1, 64, 0, stream>>>(csums, out);
}

// Round 2
// 1109.649 us; speedup vs baseline: 1.1683x; 1.1683x over previous
//
#include <hip/hip_runtime.h>
#include <math.h>

#define BTOT 262144
#define FDIM 256
#define KK 20
#define HH 64
#define MM 32

#define IMP_OFF  (BTOT * KK)            // 5242880
#define CWM_OFF  (IMP_OFF + KK)         // 5242900
#define ACT_OFF  (CWM_OFF + KK)         // 5242920
#define PAIR_OFF (ACT_OFF + 1)          // 5242921

__device__ __forceinline__ bool better(float v2, int p2, float v1, int p1) {
  return (v2 > v1) || (v2 == v1 && p2 < p1);
}

// ---------------- Top-K stage 1: per-row top-20 ----------------
__global__ void topk_stage1(const float* __restrict__ w,
                            float* __restrict__ cand_v, int* __restrict__ cand_p) {
  const int i = blockIdx.x;
  const int j = threadIdx.x;
  const int lane = j & 63, wid = j >> 6;
  __shared__ float sv[256];
  __shared__ float rv[4];
  __shared__ int rp[4];

  sv[j] = (j > i) ? w[i * 256 + j] : -1e30f;
  __syncthreads();

  for (int r = 0; r < 20; ++r) {
    float v = sv[j];
    int p = i * 256 + j;
    #pragma unroll
    for (int off = 32; off; off >>= 1) {
      float v2 = __shfl_down(v, off);
      int p2 = __shfl_down(p, off);
      if (better(v2, p2, v, p)) { v = v2; p = p2; }
    }
    if (lane == 0) { rv[wid] = v; rp[wid] = p; }
    __syncthreads();
    if (j == 0) {
      #pragma unroll
      for (int t = 1; t < 4; ++t)
        if (better(rv[t], rp[t], v, p)) { v = rv[t]; p = rp[t]; }
      cand_v[i * 20 + r] = v;
      cand_p[i * 20 + r] = p;
      sv[p & 255] = -2e30f;
    }
    __syncthreads();
  }
}

// ---------------- Top-K stage 2: merge 256*20 candidates ----------------
#define NC 5120
__global__ void topk_stage2(const float* __restrict__ cand_v, const int* __restrict__ cand_p,
                            int* __restrict__ pij, float* __restrict__ out) {
  const int tid = threadIdx.x;
  const int lane = tid & 63, wid = tid >> 6;
  __shared__ float sv[NC];
  __shared__ int sp[NC];
  __shared__ float rv[4];
  __shared__ int rp[4], rq[4];
  __shared__ float selv[20];
  __shared__ int selp[20];

  for (int t = tid; t < NC; t += 256) { sv[t] = cand_v[t]; sp[t] = cand_p[t]; }
  __syncthreads();

  for (int r = 0; r < 20; ++r) {
    float v = -4e30f;
    int p = 0x7fffffff, q = 0;
    for (int t = tid; t < NC; t += 256) {
      float vv = sv[t];
      int pp = sp[t];
      if (better(vv, pp, v, p)) { v = vv; p = pp; q = t; }
    }
    #pragma unroll
    for (int off = 32; off; off >>= 1) {
      float v2 = __shfl_down(v, off);
      int p2 = __shfl_down(p, off);
      int q2 = __shfl_down(q, off);
      if (better(v2, p2, v, p)) { v = v2; p = p2; q = q2; }
    }
    if (lane == 0) { rv[wid] = v; rp[wid] = p; rq[wid] = q; }
    __syncthreads();
    if (tid == 0) {
      #pragma unroll
      for (int t = 1; t < 4; ++t)
        if (better(rv[t], rp[t], v, p)) { v = rv[t]; p = rp[t]; q = rq[t]; }
      selv[r] = v;
      selp[r] = p;
      sv[q] = -3e30f;
    }
    __syncthreads();
  }

  if (tid == 0) {
    int active = 0;
    for (int r = 0; r < 20; ++r) {
      int p = selp[r];
      int i = p >> 8, j = p & 255;
      float s = 1.0f / (1.0f + expf(-selv[r]));
      out[IMP_OFF + r] = s;
      out[PAIR_OFF + 2 * r] = (float)i;
      out[PAIR_OFF + 2 * r + 1] = (float)j;
      if (s > 0.1f) active++;
      pij[r] = i;
      pij[20 + r] = j;
    }
    out[ACT_OFF] = (float)active;
  }
}

// ---------------- Main kernel ----------------
// 256 threads = 256 samples/block. x staged through LDS in 32-feature chunks
// (coalesced global float4 reads; pad-33 LDS stride -> 2-way bank aliasing, free).
// Outputs staged in LDS (reusing x buffer) -> coalesced float4 write-out.
#define FCH 32
#define NCHUNK (FDIM / FCH)   // 8
#define XSTR 33               // LDS row stride (floats)

__global__ __launch_bounds__(256, 3) void id_main(
    const float* __restrict__ x,
    const float* __restrict__ Wc1, const float* __restrict__ bc1,
    const float* __restrict__ Wc2, const float* __restrict__ bc2,
    const float* __restrict__ W1, const float* __restrict__ b1,
    const float* __restrict__ W2, const float* __restrict__ b2,
    const float* __restrict__ W3, const float* __restrict__ b3,
    const int* __restrict__ pij,
    float* __restrict__ ctx_sums,
    float* __restrict__ out) {
  __shared__ __align__(16) float xs[256 * XSTR];   // 33792 B; reused as out-stage
  __shared__ float csum[KK];

  const int tid = threadIdx.x;
  const int b0 = blockIdx.x * 256;
  if (tid < KK) csum[tid] = 0.0f;

  // pair columns: uniform -> SGPRs
  int pcol[2 * KK];
  #pragma unroll
  for (int i = 0; i < 2 * KK; ++i) pcol[i] = pij[i];

  float h[HH];
  #pragma unroll
  for (int j = 0; j < HH; ++j) h[j] = bc1[j];
  float pv[2 * KK];
  #pragma unroll
  for (int i = 0; i < 2 * KK; ++i) pv[i] = 0.0f;

  const int srow = tid >> 3;       // 0..31
  const int quad = tid & 7;        // 0..7
  const float* __restrict__ xrow_lds = &xs[tid * XSTR];

  #pragma unroll 1
  for (int c = 0; c < NCHUNK; ++c) {
    const int f0 = c * FCH;
    __syncthreads();   // previous chunk's readers done before overwrite
    // ---- stage chunk: 256 rows x 32 feats, coalesced float4 ----
    const float* __restrict__ xg = x + (size_t)(b0 + srow) * FDIM + f0 + quad * 4;
    #pragma unroll
    for (int r = 0; r < 8; ++r) {
      const float4 v = *(const float4*)(xg + (size_t)r * 32 * FDIM);
      float* d = &xs[(srow + r * 32) * XSTR + quad * 4];
      d[0] = v.x; d[1] = v.y; d[2] = v.z; d[3] = v.w;
    }
    __syncthreads();
    // ---- ctx hidden accumulation over this chunk ----
    #pragma unroll 2
    for (int f = 0; f < FCH; ++f) {
      const float xv = xrow_lds[f];
      const float* __restrict__ w0 = Wc1 + (size_t)(f0 + f) * HH;
      #pragma unroll
      for (int j = 0; j < HH; ++j) h[j] = fmaf(xv, w0[j], h[j]);
    }
    // ---- pair-column extraction (uniform compare/branch) ----
    #pragma unroll
    for (int i = 0; i < 2 * KK; ++i) {
      const int cc = pcol[i];
      if (cc >= f0 && cc < f0 + FCH) pv[i] = xrow_lds[cc - f0];
    }
  }

  // ---- ctx output layer ----
  float ctx[KK];
  #pragma unroll
  for (int k = 0; k < KK; ++k) ctx[k] = bc2[k];
  #pragma unroll 2
  for (int j = 0; j < HH; ++j) {
    const float hj = fmaxf(h[j], 0.0f);
    const float* __restrict__ wr = Wc2 + j * KK;
    #pragma unroll
    for (int k = 0; k < KK; ++k) ctx[k] = fmaf(hj, wr[k], ctx[k]);
  }
  #pragma unroll
  for (int k = 0; k < KK; ++k) ctx[k] = 1.0f / (1.0f + expf(-ctx[k]));

  __syncthreads();   // all xs readers done; reuse xs as out-stage
  float* __restrict__ so = xs;

  // ---- 20 pair MLPs (register compute, uniform weight loads) ----
  #pragma unroll 1
  for (int k = 0; k < KK; ++k) {
    const float pa = pv[k];
    const float pb = pv[KK + k];
    const float* __restrict__ w1k = W1 + (size_t)k * 2 * HH;
    const float* __restrict__ b1k = b1 + (size_t)k * HH;
    const float* __restrict__ w2k = W2 + (size_t)k * HH * MM;
    const float* __restrict__ b2k = b2 + (size_t)k * MM;

    float h2[MM];
    #pragma unroll
    for (int m = 0; m < MM; ++m) h2[m] = b2k[m];

    #pragma unroll 1
    for (int half = 0; half < 2; ++half) {
      float h1[32];
      #pragma unroll
      for (int j = 0; j < 32; ++j) {
        const int jj = half * 32 + j;
        h1[j] = fmaxf(fmaf(pa, w1k[jj], fmaf(pb, w1k[HH + jj], b1k[jj])), 0.0f);
      }
      const float* __restrict__ w2h = w2k + half * 32 * MM;
      #pragma unroll 2
      for (int j = 0; j < 32; ++j) {
        const float hj = h1[j];
        const float* __restrict__ wr = w2h + j * MM;
        #pragma unroll
        for (int m = 0; m < MM; ++m) h2[m] = fmaf(hj, wr[m], h2[m]);
      }
    }

    const float* __restrict__ w3k = W3 + (size_t)k * MM;
    float o = b3[k];
    #pragma unroll
    for (int m = 0; m < MM; ++m) o = fmaf(fmaxf(h2[m], 0.0f), w3k[m], o);

    so[tid * KK + k] = o * ctx[k];
  }

  // ---- ctx mean: wave shuffle -> LDS -> global atomic ----
  const int lane = tid & 63;
  #pragma unroll 1
  for (int k = 0; k < KK; ++k) {
    float v = ctx[k];
    #pragma unroll
    for (int off = 32; off; off >>= 1) v += __shfl_down(v, off);
    if (lane == 0) atomicAdd(&csum[k], v);
  }
  __syncthreads();   // so[] fully written + csum done
  if (tid < KK) atomicAdd(&ctx_sums[tid], csum[tid]);

  // ---- coalesced write-out: 256*20 floats = 1280 float4 ----
  const float4* __restrict__ sof = (const float4*)so;
  float4* __restrict__ og = (float4*)(out + (size_t)b0 * KK);
  #pragma unroll
  for (int i = 0; i < 5; ++i) og[tid + i * 256] = sof[tid + i * 256];
}

__global__ void id_finalize(const float* __restrict__ ctx_sums, float* __restrict__ out) {
  const int k = threadIdx.x;
  if (k < KK) out[CWM_OFF + k] = ctx_sums[k] * (1.0f / (float)BTOT);
}

extern "C" void kernel_launch(void* const* d_in, const int* in_sizes, int n_in,
                              void* d_out, int out_size, void* d_ws, size_t ws_size,
                              hipStream_t stream) {
  const float* x   = (const float*)d_in[0];
  const float* iw  = (const float*)d_in[1];
  const float* Wc1 = (const float*)d_in[2];
  const float* bc1 = (const float*)d_in[3];
  const float* Wc2 = (const float*)d_in[4];
  const float* bc2 = (const float*)d_in[5];
  const float* W1  = (const float*)d_in[6];
  const float* b1  = (const float*)d_in[7];
  const float* W2  = (const float*)d_in[8];
  const float* b2  = (const float*)d_in[9];
  const float* W3  = (const float*)d_in[10];
  const float* b3  = (const float*)d_in[11];
  float* out = (float*)d_out;

  float* wsf    = (float*)d_ws;
  float* cand_v = wsf;                  // 5120 floats
  int*   cand_p = (int*)(wsf + 5120);   // 5120 ints
  int*   pij    = (int*)(wsf + 10240);  // 40 ints
  float* csums  = wsf + 10280;          // 20 floats

  hipMemsetAsync(csums, 0, KK * sizeof(float), stream);
  topk_stage1<<<256, 256, 0, stream>>>(iw, cand_v, cand_p);
  topk_stage2<<<1, 256, 0, stream>>>(cand_v, cand_p, pij, out);
  id_main<<<BTOT / 256, 256, 0, stream>>>(x, Wc1, bc1, Wc2, bc2, W1, b1, W2, b2, W3, b3,
                                          pij, csums, out);
  id_finalize<<<1, 64, 0, stream>>>(csums, out);
}